// Round 15
// baseline (163.944 us; speedup 1.0000x reference)
//
#include <hip/hip_runtime.h>
#include <hip/hip_bf16.h>

// LeWinAttention: q/kv projection + scrambled-reshape windowed attention + out projection.
// q buffer: old layout [b][512 o][16384 pos]. K/V buffers: interleaved layout
// [bkv][i=pos>>6][512 oo][64 d] (contiguous 16KB per k_proj block).
// Round 15: k_cast FUSED into k_proj (f32 two-phase transpose, LDS tile unioned
// with SC2); q pre-scaled by 0.125*log2e so k_attn softmax is bare exp2f.

typedef unsigned short u16;
using bfrag = __attribute__((ext_vector_type(8))) short;   // 8 x bf16
using ffrag = __attribute__((ext_vector_type(4))) float;   // 4 x f32 accum
using s4v   = __attribute__((ext_vector_type(4))) short;   // 4 x bf16 (8B)
using u32x4 = __attribute__((ext_vector_type(4))) unsigned int;  // 16B, nt-store capable

#define MFMA16(a, b, c) __builtin_amdgcn_mfma_f32_16x16x32_bf16((a), (b), (c), 0, 0, 0)
#define QSCALE 0.1803368801111204f   // 0.125 * log2(e)

__device__ __forceinline__ u16 f2bf(float f) {
    __hip_bfloat16 h = __float2bfloat16(f);
    u16 u;
    __builtin_memcpy(&u, &h, 2);
    return u;
}

// bijective slot swizzle: distinct over {pos=base+lr} AND {pos=8k+e} patterns
__device__ __forceinline__ int sw(int p) { return (p ^ (p >> 3)) & 15; }

// ---------------------------------------------------------------------------
// Kernel 0: cast Wq (512x128), Wkv (1024x128), Wout (128x512) f32 -> bf16.
// ---------------------------------------------------------------------------
__global__ __launch_bounds__(256) void k_prep(
    const float* __restrict__ Wq, const float* __restrict__ Wkv,
    const float* __restrict__ Wout, u16* __restrict__ WB, u16* __restrict__ WoutB)
{
    int i8 = (blockIdx.x * 256 + threadIdx.x) * 8;
    const float* src;
    u16* dst;
    if (i8 < 65536)       { src = Wq + i8;            dst = WB + i8; }
    else if (i8 < 196608) { src = Wkv + (i8 - 65536); dst = WB + i8; }
    else                  { src = Wout + (i8 - 196608); dst = WoutB + (i8 - 196608); }
    float4 a = *(const float4*)src;
    float4 b = *(const float4*)(src + 4);
    u16 tmp[8];
    tmp[0] = f2bf(a.x); tmp[1] = f2bf(a.y); tmp[2] = f2bf(a.z); tmp[3] = f2bf(a.w);
    tmp[4] = f2bf(b.x); tmp[5] = f2bf(b.y); tmp[6] = f2bf(b.z); tmp[7] = f2bf(b.w);
    *(uint4*)dst = *(uint4*)tmp;
}

// ---------------------------------------------------------------------------
// Kernel 1: projection GEMM + RoPE epilogue, FUSED transpose-cast of x/skip.
// Phase 1: stage x f32 [c][pos] -> LT (pitch 65).  Phase 2: transpose-read,
// f2bf, write BT swizzled (b128).  Phase 3: SC2 stage (unions LT) + MFMA.
// q epilogue pre-scales by QSCALE (k_attn uses bare exp2f).
// grid = (256 pos-tiles of 64, 40 row-tiles).
// ---------------------------------------------------------------------------
__global__ __launch_bounds__(256, 4) void k_proj(
    const float* __restrict__ x, const float* __restrict__ skip,
    const float* __restrict__ sinp, const float* __restrict__ cosp,
    const u16* __restrict__ WB,
    u16* __restrict__ qb, u16* __restrict__ kbuf, u16* __restrict__ vbuf)
{
    __shared__ u16 BT[64 * 128];                  // bf16 x-tile -> repack tile
    __shared__ __align__(16) float UN[128 * 65];  // f32 x-tile, then reused as SC2
    float2 (*SC2)[33] = (float2(*)[33])UN;        // [o&63][s] {sin,cos}, pitch 33

    const int t = threadIdx.x;
    const int pos0 = blockIdx.x * 64;
    const int tr = blockIdx.y;
    const int w = t >> 6, l = t & 63, lr = l & 15, lg = l >> 4;

    int WBrow, plane, mode;  // mode: 0 none (v), 1 q-rope, 2 k-rope
    u16* dst;
    const bool contig = (tr >= 8);
    if (tr < 8) {
        int b = tr >> 2, o0 = (tr & 3) * 128;
        WBrow = o0; plane = b; mode = 1;
        dst = qb + (size_t)b * 8388608 + (size_t)o0 * 16384;   // old layout
    } else {
        int t2 = tr - 8;
        int bkv = t2 >> 3, oo0 = (t2 & 7) * 128;
        WBrow = 512 + oo0; plane = bkv;
        if (oo0 < 512) {
            dst = kbuf + (size_t)bkv * 8388608 + (size_t)blockIdx.x * 32768 + (size_t)oo0 * 64;
            mode = 2;
        } else {
            dst = vbuf + (size_t)bkv * 8388608 + (size_t)blockIdx.x * 32768 + (size_t)(oo0 - 512) * 64;
            mode = 0;
        }
    }

    // --- Phase 1: stage x/skip f32 tile [128 c][64 pos] -> LT (k_cast pattern)
    const float* src = (plane < 2) ? (x + (size_t)plane * 2097152)
                                   : (skip + (size_t)(plane - 2) * 2097152);
#pragma unroll
    for (int it = 0; it < 8; ++it) {
        int idx = it * 256 + t;
        int c = idx >> 4, p4 = (idx & 15) * 4;
        float4 v = *(const float4*)(src + (size_t)c * 16384 + pos0 + p4);
        UN[c * 65 + p4 + 0] = v.x;
        UN[c * 65 + p4 + 1] = v.y;
        UN[c * 65 + p4 + 2] = v.z;
        UN[c * 65 + p4 + 3] = v.w;
    }
    __syncthreads();   // B1: LT ready

    // --- Phase 2: transpose-read LT, cast, write BT swizzled (b128)
#pragma unroll
    for (int it = 0; it < 4; ++it) {
        int g = it * 256 + t;
        int pos_l = g >> 4, chunk = g & 15;
        u16 tmp[8];
#pragma unroll
        for (int j = 0; j < 8; ++j)
            tmp[j] = f2bf(UN[(chunk * 8 + j) * 65 + pos_l]);
        *(uint4*)&BT[pos_l * 128 + ((chunk ^ sw(pos_l)) << 3)] = *(uint4*)tmp;
    }
    __syncthreads();   // B2: BT ready, LT region free (becomes SC2)

    // --- Phase 3: SC2 stage (coalesced 128B rows) overlapping the MFMA loop
    const int hh = pos0 >> 7;            // posb>>7, block-uniform
    const int wwhi = blockIdx.x & 1;     // ww>>6, block-uniform
    if (mode != 0) {
        const int hb = hh >> 6;
        const int ridx = (hh & 63) * 2 + wwhi;
#pragma unroll
        for (int e = 0; e < 2; ++e) {
            int g = e * 256 + t;          // 0..511
            int row = g >> 3;             // o&63
            int q = g & 7;                // float4 slot in the 32-f row
            size_t base = ((size_t)(row * 2 + hb) * 128 + ridx) * 32 + q * 4;
            float4 sv4 = *(const float4*)(sinp + base);
            float4 cv4 = *(const float4*)(cosp + base);
            SC2[row][q * 4 + 0] = float2{sv4.x, cv4.x};
            SC2[row][q * 4 + 1] = float2{sv4.y, cv4.y};
            SC2[row][q * 4 + 2] = float2{sv4.z, cv4.z};
            SC2[row][q * 4 + 3] = float2{sv4.w, cv4.w};
        }
    }

    ffrag zf = {0.f, 0.f, 0.f, 0.f};
    ffrag acc[4][2];   // [mb = pos 16-block][nb = o 16-block within wave's 32]
#pragma unroll
    for (int mb = 0; mb < 4; ++mb)
#pragma unroll
        for (int nb = 0; nb < 2; ++nb) acc[mb][nb] = zf;

#pragma unroll
    for (int kk = 0; kk < 4; ++kk) {
        bfrag A[4], B[2];
#pragma unroll
        for (int mb = 0; mb < 4; ++mb) {
            int pos_l = mb * 16 + lr;
            A[mb] = *(const bfrag*)&BT[pos_l * 128 + (((kk * 4 + lg) ^ sw(pos_l)) << 3)];
        }
#pragma unroll
        for (int nb = 0; nb < 2; ++nb)
            B[nb] = *(const bfrag*)(WB + (size_t)(WBrow + w * 32 + nb * 16 + lr) * 128 + kk * 32 + lg * 8);
#pragma unroll
        for (int mb = 0; mb < 4; ++mb)
#pragma unroll
            for (int nb = 0; nb < 2; ++nb)
                acc[mb][nb] = MFMA16(A[mb], B[nb], acc[mb][nb]);
    }

    __syncthreads();   // B3: SC2 writes visible; BT reads done -> repack reuse

    // epilogue: lane holds 4 consecutive pos (register r) at one o (lane).
    // RoPE active iff pos_l < 32 <=> mb < 2. q output pre-scaled by QSCALE.
#pragma unroll
    for (int mb = 0; mb < 4; ++mb) {
        const bool roped = (mode != 0) && (mb < 2);
#pragma unroll
        for (int nb = 0; nb < 2; ++nb) {
            int o_l = w * 32 + nb * 16 + lr;
            int p0 = mb * 16 + lg * 4;          // pos_l base of quad
            ffrag v4 = acc[mb][nb];
            if (roped) {
                const int ob63 = o_l & 63;
#pragma unroll
                for (int r = 0; r < 4; ++r) {
                    float2 sc = SC2[ob63][p0 + r];       // one b64 read: {sin,cos}
                    float sg = (r & 1) ? sc.x : -sc.x;   // rotate_half: -even, +odd
                    v4[r] = (mode == 1) ? v4[r] * (sc.y + sg)        // q
                                        : v4[r] * (1.f + sg) + sc.y; // k (ref's "+cos")
                }
            }
            if (mode == 1) {     // pre-scale q by 0.125*log2e (softmax uses exp2)
#pragma unroll
                for (int r = 0; r < 4; ++r) v4[r] *= QSCALE;
            }
            s4v pk;
            pk[0] = (short)f2bf(v4[0]); pk[1] = (short)f2bf(v4[1]);
            pk[2] = (short)f2bf(v4[2]); pk[3] = (short)f2bf(v4[3]);
            int slot = p0 >> 3;                 // 0..7
            *(s4v*)&BT[o_l * 64 + ((slot ^ (o_l & 7)) << 3) + (p0 & 4)] = pk;
        }
    }

    // PER-WAVE store (same-wave producer/consumer; NO final barrier):
    // wave w's epilogue wrote exactly repack rows [w*32, w*32+32).
#pragma unroll
    for (int it = 0; it < 4; ++it) {
        int i = it * 64 + l;                 // 0..255 within wave's 32-row region
        int row = w * 32 + (i >> 3);
        int slot = i & 7;
        u32x4 v = *(const u32x4*)&BT[row * 64 + ((slot ^ (row & 7)) << 3)];
        size_t goff = contig ? ((size_t)row * 64 + slot * 8)
                             : ((size_t)row * 16384 + pos0 + slot * 8);
        __builtin_nontemporal_store(v, (u32x4*)(dst + goff));
    }
}

// ---------------------------------------------------------------------------
// Kernel 2: windowed attention — 4 waves x 64 q-rows. Round-15: softmax is
// bare exp2f (q pre-scaled in k_proj). Otherwise identical to round 14.
// ---------------------------------------------------------------------------
__global__ __launch_bounds__(256) void k_attn(
    const u16* __restrict__ qb, const u16* __restrict__ kbuf,
    const u16* __restrict__ vbuf, u16* __restrict__ ob)
{
    __shared__ u16 Ks[64 * 64];      // [j][d-chunk ^ (j&7)]
    __shared__ u16 Vt[64 * 64];      // [d][j-chunk ^ s(d)], s(d)=(d&7)^((d>>3)&7)
    __shared__ u16 Ps[4][64 * 40];   // per wave: [i_local 64][j-half 32, pitch 40]
    __shared__ float Lbuf[256];

    const int bp = blockIdx.x;
    const int t = threadIdx.x, w = t >> 6, l = t & 63, lr = l & 15, lg = l >> 4;

    const u16* Qg = qb + (size_t)bp * 16384 + w * 4096;   // wave's 64 q-rows

    bfrag Qf[4][2];
#pragma unroll
    for (int rb = 0; rb < 4; ++rb)
#pragma unroll
        for (int dk = 0; dk < 2; ++dk)
            Qf[rb][dk] = *(const bfrag*)(Qg + (rb * 16 + lr) * 64 + dk * 32 + lg * 8);

    ffrag zf = {0.f, 0.f, 0.f, 0.f};
    ffrag Oacc[4][4];
#pragma unroll
    for (int rb = 0; rb < 4; ++rb)
#pragma unroll
        for (int sb = 0; sb < 4; ++sb) Oacc[rb][sb] = zf;
    float Lp[4] = {0.f, 0.f, 0.f, 0.f};

    // staging: EVERY thread stages 32B of K and 32B of V (row srow, quarter sq)
    const int srow = t >> 2, sq = t & 3;
    const size_t kvoff = (size_t)(bp >> 8) * 8388608 + (size_t)(bp & 255) * 128;
    const u16* gK = kbuf + kvoff;
    const u16* gV = vbuf + kvoff;
    #define KVOFF(c) ((size_t)(((c) & 3) * 64 + srow) * 32768 + (size_t)(((c) >> 2) * 64) + sq * 16)

    uint4 k0 = *(const uint4*)(gK + KVOFF(0));           // prefetch chunk 0
    uint4 k1 = *(const uint4*)(gK + KVOFF(0) + 8);
    uint4 v0 = *(const uint4*)(gV + KVOFF(0));
    uint4 v1 = *(const uint4*)(gV + KVOFF(0) + 8);

    const int chv = srow >> 3, jl = srow & 7;            // V-transpose coords

    for (int c = 0; c < 8; ++c) {
        __syncthreads();
        *(uint4*)&Ks[srow * 64 + (((sq * 2) ^ (srow & 7)) << 3)] = k0;
        *(uint4*)&Ks[srow * 64 + (((sq * 2 + 1) ^ (srow & 7)) << 3)] = k1;
        {
            u16 tmp[16];
            *(uint4*)&tmp[0] = v0;
            *(uint4*)&tmp[8] = v1;
#pragma unroll
            for (int e = 0; e < 16; ++e) {
                int d = sq * 16 + e;
                int s = (d & 7) ^ ((d >> 3) & 7);
                Vt[d * 64 + ((chv ^ s) << 3) + jl] = tmp[e];   // V^T[d][j]
            }
        }
        __syncthreads();
        if (c < 7) {
            k0 = *(const uint4*)(gK + KVOFF(c + 1));
            k1 = *(const uint4*)(gK + KVOFF(c + 1) + 8);
            v0 = *(const uint4*)(gV + KVOFF(c + 1));
            v1 = *(const uint4*)(gV + KVOFF(c + 1) + 8);
        }

#pragma unroll
        for (int jh = 0; jh < 2; ++jh) {
#pragma unroll
            for (int jtl = 0; jtl < 2; ++jtl) {
                const int jt = jh * 2 + jtl;
                bfrag Kf[2];
#pragma unroll
                for (int dk = 0; dk < 2; ++dk)
                    Kf[dk] = *(const bfrag*)&Ks[(jt * 16 + lr) * 64 + (((dk * 4 + lg) ^ (lr & 7)) << 3)];
#pragma unroll
                for (int rb = 0; rb < 4; ++rb) {
                    ffrag sf = zf;
                    __builtin_amdgcn_s_setprio(1);
                    sf = MFMA16(Kf[0], Qf[rb][0], sf);   // D[j_loc=lg*4+r][i_loc=lr]
                    sf = MFMA16(Kf[1], Qf[rb][1], sf);
                    __builtin_amdgcn_s_setprio(0);
                    float e0 = exp2f(sf[0]);    // q pre-scaled by 0.125*log2e
                    float e1 = exp2f(sf[1]);
                    float e2 = exp2f(sf[2]);
                    float e3 = exp2f(sf[3]);
                    Lp[rb] += (e0 + e1) + (e2 + e3);
                    s4v pk;
                    pk[0] = (short)f2bf(e0); pk[1] = (short)f2bf(e1);
                    pk[2] = (short)f2bf(e2); pk[3] = (short)f2bf(e3);
                    *(s4v*)&Ps[w][(rb * 16 + lr) * 40 + jtl * 16 + lg * 4] = pk;
                }
            }

            bfrag Vf[4];
#pragma unroll
            for (int sb = 0; sb < 4; ++sb) {
                int d = sb * 16 + lr;
                int s = (d & 7) ^ ((d >> 3) & 7);
                Vf[sb] = *(const bfrag*)&Vt[d * 64 + (((jh * 4 + lg) ^ s) << 3)];
            }
            __builtin_amdgcn_s_setprio(1);
#pragma unroll
            for (int rb = 0; rb < 4; ++rb) {
                bfrag Pf = *(const bfrag*)&Ps[w][(rb * 16 + lr) * 40 + lg * 8];
#pragma unroll
                for (int sb = 0; sb < 4; ++sb)
                    Oacc[rb][sb] = MFMA16(Pf, Vf[sb], Oacc[rb][sb]);  // D[i=lg*4+r][d=lr]
            }
            __builtin_amdgcn_s_setprio(0);
        }
    }
    #undef KVOFF

#pragma unroll
    for (int rb = 0; rb < 4; ++rb) {
        float v = Lp[rb];
        v += __shfl_xor(v, 16);
        v += __shfl_xor(v, 32);
        if (lg == 0) Lbuf[w * 64 + rb * 16 + lr] = v;
    }
    // same-wave producer/consumer: no barrier needed
    u16* og = ob + (size_t)bp * 16384 + w * 4096;
#pragma unroll
    for (int rb = 0; rb < 4; ++rb)
#pragma unroll
        for (int r = 0; r < 4; ++r) {
            float inv = 1.f / Lbuf[w * 64 + rb * 16 + lg * 4 + r];
#pragma unroll
            for (int sb = 0; sb < 4; ++sb)
                og[(rb * 16 + lg * 4 + r) * 64 + sb * 16 + lr] = f2bf(Oacc[rb][sb][r] * inv);
        }
}

// ---------------------------------------------------------------------------
// Kernel 3: out projection out[b][o2][pos] = sum_c2 WoutB[o2][c2]*ob[b][c2][pos].
// Final f32 output is never re-read -> NON-TEMPORAL stores.
// ---------------------------------------------------------------------------
__global__ __launch_bounds__(256) void k_out(
    const u16* __restrict__ ob, const u16* __restrict__ WoutB,
    float* __restrict__ out)
{
    __shared__ u16 OT[64 * 128];
    const int t = threadIdx.x, w = t >> 6, l = t & 63, lr = l & 15, lg = l >> 4;
    const int pos0 = blockIdx.x * 64;
    const int b = blockIdx.y;
    const u16* obp = ob + (size_t)b * 8388608;
    float* op = out + (size_t)b * 2097152;

    ffrag zf = {0.f, 0.f, 0.f, 0.f};
    ffrag acc[2][4];
#pragma unroll
    for (int rb = 0; rb < 2; ++rb)
#pragma unroll
        for (int nb = 0; nb < 4; ++nb) acc[rb][nb] = zf;

    for (int kc = 0; kc < 4; ++kc) {
        __syncthreads();
#pragma unroll
        for (int it = 0; it < 4; ++it) {
            int g = it * 256 + t;
            int cl = g >> 3, pk = g & 7;
            uint4 v = *(const uint4*)(obp + (size_t)(kc * 128 + cl) * 16384 + pos0 + pk * 8);
            u16 tmp[8];
            *(uint4*)tmp = v;
#pragma unroll
            for (int e = 0; e < 8; ++e) {
                int pos_l = pk * 8 + e;
                OT[pos_l * 128 + (((cl >> 3) ^ sw(pos_l)) << 3) + (cl & 7)] = tmp[e];
            }
        }
        __syncthreads();

#pragma unroll
        for (int kk = 0; kk < 4; ++kk) {
            bfrag Af[2];
#pragma unroll
            for (int rb = 0; rb < 2; ++rb)
                Af[rb] = *(const bfrag*)(WoutB + (size_t)(w * 32 + rb * 16 + lr) * 512 + kc * 128 + kk * 32 + lg * 8);
#pragma unroll
            for (int nb = 0; nb < 4; ++nb) {
                int pos_l = nb * 16 + lr;
                bfrag B = *(const bfrag*)&OT[pos_l * 128 + (((kk * 4 + lg) ^ sw(pos_l)) << 3)];
#pragma unroll
                for (int rb = 0; rb < 2; ++rb)
                    acc[rb][nb] = MFMA16(Af[rb], B, acc[rb][nb]);
            }
        }
    }

#pragma unroll
    for (int rb = 0; rb < 2; ++rb)
#pragma unroll
        for (int nb = 0; nb < 4; ++nb)
#pragma unroll
            for (int r = 0; r < 4; ++r)
                __builtin_nontemporal_store(acc[rb][nb][r],
                    op + (size_t)(w * 32 + rb * 16 + lg * 4 + r) * 16384 + pos0 + nb * 16 + lr);
}

// ---------------------------------------------------------------------------
extern "C" void kernel_launch(void* const* d_in, const int* in_sizes, int n_in,
                              void* d_out, int out_size, void* d_ws, size_t ws_size,
                              hipStream_t stream) {
    const float* x    = (const float*)d_in[0];
    const float* skip = (const float*)d_in[1];
    const float* sinp = (const float*)d_in[2];
    const float* cosp = (const float*)d_in[3];
    const float* Wq   = (const float*)d_in[4];
    const float* Wkv  = (const float*)d_in[5];
    const float* Wout = (const float*)d_in[6];
    float* out = (float*)d_out;

    // workspace (u16 units): qb 16.7M | kbuf 33.5M | vbuf 33.5M | WB | WoutB
    u16* qb    = (u16*)d_ws;
    u16* kbp   = qb + (size_t)16777216;
    u16* vbp   = kbp + (size_t)33554432;
    u16* WBp   = vbp + (size_t)33554432;
    u16* WoutB = WBp + (size_t)196608;

    hipLaunchKernelGGL(k_prep, dim3(128), dim3(256), 0, stream,
                       Wq, Wkv, Wout, WBp, WoutB);
    hipLaunchKernelGGL(k_proj, dim3(256, 40), dim3(256), 0, stream,
                       x, skip, sinp, cosp, WBp, qb, kbp, vbp);
    hipLaunchKernelGGL(k_attn, dim3(1024), dim3(256), 0, stream,
                       qb, kbp, vbp, qb /* in-place output over q */);
    hipLaunchKernelGGL(k_out, dim3(256, 2), dim3(256), 0, stream,
                       qb, WoutB, out);
}

// Round 16
// 156.847 us; speedup vs baseline: 1.0452x; 1.0452x over previous
//
#include <hip/hip_runtime.h>
#include <hip/hip_bf16.h>

// LeWinAttention: q/kv projection + scrambled-reshape windowed attention + out projection.
// q buffer: old layout [b][512 o][16384 pos]. K/V buffers: interleaved layout
// [bkv][i=pos>>6][512 oo][64 d] (contiguous 16KB per k_proj block).
// Round 16: REVERT round-15 fusion (k_cast restored; it was a net -13us loss).
// Keep q pre-scale by 0.125*log2e + bare exp2f softmax in k_attn.

typedef unsigned short u16;
using bfrag = __attribute__((ext_vector_type(8))) short;   // 8 x bf16
using ffrag = __attribute__((ext_vector_type(4))) float;   // 4 x f32 accum
using s4v   = __attribute__((ext_vector_type(4))) short;   // 4 x bf16 (8B)
using u32x4 = __attribute__((ext_vector_type(4))) unsigned int;  // 16B, nt-store capable

#define MFMA16(a, b, c) __builtin_amdgcn_mfma_f32_16x16x32_bf16((a), (b), (c), 0, 0, 0)
#define QSCALE 0.1803368801111204f   // 0.125 * log2(e)

__device__ __forceinline__ u16 f2bf(float f) {
    __hip_bfloat16 h = __float2bfloat16(f);
    u16 u;
    __builtin_memcpy(&u, &h, 2);
    return u;
}

// bijective slot swizzle: distinct over {pos=base+lr} AND {pos=8k+e} patterns
__device__ __forceinline__ int sw(int p) { return (p ^ (p >> 3)) & 15; }

// ---------------------------------------------------------------------------
// Kernel 0: cast Wq (512x128), Wkv (1024x128), Wout (128x512) f32 -> bf16.
// ---------------------------------------------------------------------------
__global__ __launch_bounds__(256) void k_prep(
    const float* __restrict__ Wq, const float* __restrict__ Wkv,
    const float* __restrict__ Wout, u16* __restrict__ WB, u16* __restrict__ WoutB)
{
    int i8 = (blockIdx.x * 256 + threadIdx.x) * 8;
    const float* src;
    u16* dst;
    if (i8 < 65536)       { src = Wq + i8;            dst = WB + i8; }
    else if (i8 < 196608) { src = Wkv + (i8 - 65536); dst = WB + i8; }
    else                  { src = Wout + (i8 - 196608); dst = WoutB + (i8 - 196608); }
    float4 a = *(const float4*)src;
    float4 b = *(const float4*)(src + 4);
    u16 tmp[8];
    tmp[0] = f2bf(a.x); tmp[1] = f2bf(a.y); tmp[2] = f2bf(a.z); tmp[3] = f2bf(a.w);
    tmp[4] = f2bf(b.x); tmp[5] = f2bf(b.y); tmp[6] = f2bf(b.z); tmp[7] = f2bf(b.w);
    *(uint4*)dst = *(uint4*)tmp;
}

// ---------------------------------------------------------------------------
// Kernel 1: transpose-cast x,skip f32 [c][pos] -> xb bf16 [plane][pos][c] linear.
// ---------------------------------------------------------------------------
__global__ __launch_bounds__(256) void k_cast(
    const float* __restrict__ x, const float* __restrict__ skip,
    u16* __restrict__ xb)
{
    __shared__ float LT[128 * 65];
    const int t = threadIdx.x;
    const int pos0 = blockIdx.x * 64;
    const int p = blockIdx.y;
    const float* src = (p < 2) ? (x + (size_t)p * 2097152)
                               : (skip + (size_t)(p - 2) * 2097152);
    u16* dst = xb + (size_t)p * 2097152;

#pragma unroll
    for (int it = 0; it < 8; ++it) {
        int idx = it * 256 + t;
        int c = idx >> 4, p4 = (idx & 15) * 4;
        float4 v = *(const float4*)(src + (size_t)c * 16384 + pos0 + p4);
        LT[c * 65 + p4 + 0] = v.x;
        LT[c * 65 + p4 + 1] = v.y;
        LT[c * 65 + p4 + 2] = v.z;
        LT[c * 65 + p4 + 3] = v.w;
    }
    __syncthreads();

#pragma unroll
    for (int it = 0; it < 4; ++it) {
        int g = it * 256 + t;
        int pos_l = g >> 4, chunk = g & 15;
        u16 tmp[8];
#pragma unroll
        for (int j = 0; j < 8; ++j)
            tmp[j] = f2bf(LT[(chunk * 8 + j) * 65 + pos_l]);
        *(uint4*)(dst + (size_t)(pos0 + pos_l) * 128 + chunk * 8) = *(uint4*)tmp;
    }
}

// ---------------------------------------------------------------------------
// Kernel 2: projection GEMM + RoPE epilogue (round-13 version + QSCALE on q).
// grid = (256 pos-tiles of 64, 40 row-tiles).
// ---------------------------------------------------------------------------
__global__ __launch_bounds__(256, 4) void k_proj(
    const u16* __restrict__ xb, const float* __restrict__ sinp,
    const float* __restrict__ cosp, const u16* __restrict__ WB,
    u16* __restrict__ qb, u16* __restrict__ kbuf, u16* __restrict__ vbuf)
{
    __shared__ u16 BT[64 * 128];      // stage [pos 64][c 128] -> repack [o 128][pos 64]
    __shared__ float2 SC2[64][33];    // {sin,cos} per [o&63][s], pitch 33
    const int t = threadIdx.x;
    const int pos0 = blockIdx.x * 64;
    const int tr = blockIdx.y;
    const int w = t >> 6, l = t & 63, lr = l & 15, lg = l >> 4;

    int WBrow, plane, mode;  // mode: 0 none (v), 1 q-rope, 2 k-rope
    u16* dst;
    const bool contig = (tr >= 8);
    if (tr < 8) {
        int b = tr >> 2, o0 = (tr & 3) * 128;
        WBrow = o0; plane = b; mode = 1;
        dst = qb + (size_t)b * 8388608 + (size_t)o0 * 16384;   // old layout
    } else {
        int t2 = tr - 8;
        int bkv = t2 >> 3, oo0 = (t2 & 7) * 128;
        WBrow = 512 + oo0; plane = bkv;
        if (oo0 < 512) {
            dst = kbuf + (size_t)bkv * 8388608 + (size_t)blockIdx.x * 32768 + (size_t)oo0 * 64;
            mode = 2;
        } else {
            dst = vbuf + (size_t)bkv * 8388608 + (size_t)blockIdx.x * 32768 + (size_t)(oo0 - 512) * 64;
            mode = 0;
        }
    }

    // stage x tile: xb [pos0..pos0+63][128 c] -> BT swizzled (4 uint4 / thread)
    const u16* xsrc = xb + (size_t)plane * 2097152 + (size_t)pos0 * 128;
#pragma unroll
    for (int it = 0; it < 4; ++it) {
        int li = it * 256 + t;          // 0..1023
        int row = li >> 4, chunk = li & 15;
        uint4 v = *(const uint4*)(xsrc + (size_t)row * 128 + chunk * 8);
        *(uint4*)&BT[row * 128 + ((chunk ^ sw(row)) << 3)] = v;
    }

    // stage this block's sin/cos rows interleaved (coalesced 128B rows).
    const int hh = pos0 >> 7;            // posb>>7, block-uniform
    const int wwhi = blockIdx.x & 1;     // ww>>6, block-uniform
    if (mode != 0) {
        const int hb = hh >> 6;
        const int ridx = (hh & 63) * 2 + wwhi;
#pragma unroll
        for (int e = 0; e < 2; ++e) {
            int g = e * 256 + t;          // 0..511
            int row = g >> 3;             // o&63
            int q = g & 7;                // float4 slot in the 32-f row
            size_t base = ((size_t)(row * 2 + hb) * 128 + ridx) * 32 + q * 4;
            float4 sv4 = *(const float4*)(sinp + base);
            float4 cv4 = *(const float4*)(cosp + base);
            SC2[row][q * 4 + 0] = float2{sv4.x, cv4.x};
            SC2[row][q * 4 + 1] = float2{sv4.y, cv4.y};
            SC2[row][q * 4 + 2] = float2{sv4.z, cv4.z};
            SC2[row][q * 4 + 3] = float2{sv4.w, cv4.w};
        }
    }

    ffrag zf = {0.f, 0.f, 0.f, 0.f};
    ffrag acc[4][2];   // [mb = pos 16-block][nb = o 16-block within wave's 32]
#pragma unroll
    for (int mb = 0; mb < 4; ++mb)
#pragma unroll
        for (int nb = 0; nb < 2; ++nb) acc[mb][nb] = zf;

    __syncthreads();

#pragma unroll
    for (int kk = 0; kk < 4; ++kk) {
        bfrag A[4], B[2];
#pragma unroll
        for (int mb = 0; mb < 4; ++mb) {
            int pos_l = mb * 16 + lr;
            A[mb] = *(const bfrag*)&BT[pos_l * 128 + (((kk * 4 + lg) ^ sw(pos_l)) << 3)];
        }
#pragma unroll
        for (int nb = 0; nb < 2; ++nb)
            B[nb] = *(const bfrag*)(WB + (size_t)(WBrow + w * 32 + nb * 16 + lr) * 128 + kk * 32 + lg * 8);
#pragma unroll
        for (int mb = 0; mb < 4; ++mb)
#pragma unroll
            for (int nb = 0; nb < 2; ++nb)
                acc[mb][nb] = MFMA16(A[mb], B[nb], acc[mb][nb]);
    }

    __syncthreads();  // x-tile reads AND SC2 writes complete; BT reused as repack

    // epilogue: lane holds 4 consecutive pos (register r) at one o (lane).
    // RoPE active iff pos_l < 32 <=> mb < 2. q output pre-scaled by QSCALE.
#pragma unroll
    for (int mb = 0; mb < 4; ++mb) {
        const bool roped = (mode != 0) && (mb < 2);
#pragma unroll
        for (int nb = 0; nb < 2; ++nb) {
            int o_l = w * 32 + nb * 16 + lr;
            int p0 = mb * 16 + lg * 4;          // pos_l base of quad
            ffrag v4 = acc[mb][nb];
            if (roped) {
                const int ob63 = o_l & 63;
#pragma unroll
                for (int r = 0; r < 4; ++r) {
                    float2 sc = SC2[ob63][p0 + r];       // one b64 read: {sin,cos}
                    float sg = (r & 1) ? sc.x : -sc.x;   // rotate_half: -even, +odd
                    v4[r] = (mode == 1) ? v4[r] * (sc.y + sg)        // q
                                        : v4[r] * (1.f + sg) + sc.y; // k (ref's "+cos")
                }
            }
            if (mode == 1) {     // pre-scale q by 0.125*log2e (softmax uses exp2)
#pragma unroll
                for (int r = 0; r < 4; ++r) v4[r] *= QSCALE;
            }
            s4v pk;
            pk[0] = (short)f2bf(v4[0]); pk[1] = (short)f2bf(v4[1]);
            pk[2] = (short)f2bf(v4[2]); pk[3] = (short)f2bf(v4[3]);
            int slot = p0 >> 3;                 // 0..7
            *(s4v*)&BT[o_l * 64 + ((slot ^ (o_l & 7)) << 3) + (p0 & 4)] = pk;
        }
    }

    // PER-WAVE store (same-wave producer/consumer; NO final barrier):
    // wave w's epilogue wrote exactly repack rows [w*32, w*32+32).
#pragma unroll
    for (int it = 0; it < 4; ++it) {
        int i = it * 64 + l;                 // 0..255 within wave's 32-row region
        int row = w * 32 + (i >> 3);
        int slot = i & 7;
        u32x4 v = *(const u32x4*)&BT[row * 64 + ((slot ^ (row & 7)) << 3)];
        size_t goff = contig ? ((size_t)row * 64 + slot * 8)
                             : ((size_t)row * 16384 + pos0 + slot * 8);
        __builtin_nontemporal_store(v, (u32x4*)(dst + goff));
    }
}

// ---------------------------------------------------------------------------
// Kernel 3: windowed attention — 4 waves x 64 q-rows (round-13 version:
// split staging t<128 K / t>=128 V, setprio) + bare exp2f softmax.
// ---------------------------------------------------------------------------
__global__ __launch_bounds__(256) void k_attn(
    const u16* __restrict__ qb, const u16* __restrict__ kbuf,
    const u16* __restrict__ vbuf, u16* __restrict__ ob)
{
    __shared__ u16 Ks[64 * 64];      // [j][d-chunk ^ (j&7)]
    __shared__ u16 Vt[64 * 64];      // [d][j-chunk ^ s(d)], s(d)=(d&7)^((d>>3)&7)
    __shared__ u16 Ps[4][64 * 40];   // per wave: [i_local 64][j-half 32, pitch 40]
    __shared__ float Lbuf[256];

    const int bp = blockIdx.x;
    const int t = threadIdx.x, w = t >> 6, l = t & 63, lr = l & 15, lg = l >> 4;

    const u16* Qg = qb + (size_t)bp * 16384 + w * 4096;   // wave's 64 q-rows

    bfrag Qf[4][2];
#pragma unroll
    for (int rb = 0; rb < 4; ++rb)
#pragma unroll
        for (int dk = 0; dk < 2; ++dk)
            Qf[rb][dk] = *(const bfrag*)(Qg + (rb * 16 + lr) * 64 + dk * 32 + lg * 8);

    ffrag zf = {0.f, 0.f, 0.f, 0.f};
    ffrag Oacc[4][4];
#pragma unroll
    for (int rb = 0; rb < 4; ++rb)
#pragma unroll
        for (int sb = 0; sb < 4; ++sb) Oacc[rb][sb] = zf;
    float Lp[4] = {0.f, 0.f, 0.f, 0.f};

    // staging: threads 0..127 stage K, 128..255 stage V (64B each per chunk)
    const int tk = t & 127, sj = tk >> 1, half = tk & 1;
    const bool isK = (t < 128);
    const size_t kvoff = (size_t)(bp >> 8) * 8388608 + (size_t)(bp & 255) * 128;
    const u16* gsb = (isK ? kbuf : vbuf) + kvoff;
    #define KVOFF(c) ((size_t)(((c) & 3) * 64 + sj) * 32768 + (size_t)(((c) >> 2) * 64) + half * 32)

    uint4 r0 = *(const uint4*)(gsb + KVOFF(0));          // prefetch chunk 0 (64B)
    uint4 r1 = *(const uint4*)(gsb + KVOFF(0) + 8);
    uint4 r2 = *(const uint4*)(gsb + KVOFF(0) + 16);
    uint4 r3 = *(const uint4*)(gsb + KVOFF(0) + 24);

    for (int c = 0; c < 8; ++c) {
        __syncthreads();
        if (isK) {
            *(uint4*)&Ks[sj * 64 + (((half * 4 + 0) ^ (sj & 7)) << 3)] = r0;
            *(uint4*)&Ks[sj * 64 + (((half * 4 + 1) ^ (sj & 7)) << 3)] = r1;
            *(uint4*)&Ks[sj * 64 + (((half * 4 + 2) ^ (sj & 7)) << 3)] = r2;
            *(uint4*)&Ks[sj * 64 + (((half * 4 + 3) ^ (sj & 7)) << 3)] = r3;
        } else {
            u16 tmp[32];
            *(uint4*)&tmp[0] = r0;
            *(uint4*)&tmp[8] = r1;
            *(uint4*)&tmp[16] = r2;
            *(uint4*)&tmp[24] = r3;
            const int chunk = sj >> 3, jl = sj & 7;
#pragma unroll
            for (int e = 0; e < 32; ++e) {
                int d = half * 32 + e;
                int s = (d & 7) ^ ((d >> 3) & 7);
                Vt[d * 64 + ((chunk ^ s) << 3) + jl] = tmp[e];   // V^T[d][j]
            }
        }
        __syncthreads();
        if (c < 7) {
            r0 = *(const uint4*)(gsb + KVOFF(c + 1));
            r1 = *(const uint4*)(gsb + KVOFF(c + 1) + 8);
            r2 = *(const uint4*)(gsb + KVOFF(c + 1) + 16);
            r3 = *(const uint4*)(gsb + KVOFF(c + 1) + 24);
        }

#pragma unroll
        for (int jh = 0; jh < 2; ++jh) {
#pragma unroll
            for (int jtl = 0; jtl < 2; ++jtl) {
                const int jt = jh * 2 + jtl;
                bfrag Kf[2];
#pragma unroll
                for (int dk = 0; dk < 2; ++dk)
                    Kf[dk] = *(const bfrag*)&Ks[(jt * 16 + lr) * 64 + (((dk * 4 + lg) ^ (lr & 7)) << 3)];
#pragma unroll
                for (int rb = 0; rb < 4; ++rb) {
                    ffrag sf = zf;
                    __builtin_amdgcn_s_setprio(1);
                    sf = MFMA16(Kf[0], Qf[rb][0], sf);   // D[j_loc=lg*4+r][i_loc=lr]
                    sf = MFMA16(Kf[1], Qf[rb][1], sf);
                    __builtin_amdgcn_s_setprio(0);
                    float e0 = exp2f(sf[0]);    // q pre-scaled by 0.125*log2e
                    float e1 = exp2f(sf[1]);
                    float e2 = exp2f(sf[2]);
                    float e3 = exp2f(sf[3]);
                    Lp[rb] += (e0 + e1) + (e2 + e3);
                    s4v pk;
                    pk[0] = (short)f2bf(e0); pk[1] = (short)f2bf(e1);
                    pk[2] = (short)f2bf(e2); pk[3] = (short)f2bf(e3);
                    *(s4v*)&Ps[w][(rb * 16 + lr) * 40 + jtl * 16 + lg * 4] = pk;
                }
            }

            bfrag Vf[4];
#pragma unroll
            for (int sb = 0; sb < 4; ++sb) {
                int d = sb * 16 + lr;
                int s = (d & 7) ^ ((d >> 3) & 7);
                Vf[sb] = *(const bfrag*)&Vt[d * 64 + (((jh * 4 + lg) ^ s) << 3)];
            }
            __builtin_amdgcn_s_setprio(1);
#pragma unroll
            for (int rb = 0; rb < 4; ++rb) {
                bfrag Pf = *(const bfrag*)&Ps[w][(rb * 16 + lr) * 40 + lg * 8];
#pragma unroll
                for (int sb = 0; sb < 4; ++sb)
                    Oacc[rb][sb] = MFMA16(Pf, Vf[sb], Oacc[rb][sb]);  // D[i=lg*4+r][d=lr]
            }
            __builtin_amdgcn_s_setprio(0);
        }
    }
    #undef KVOFF

#pragma unroll
    for (int rb = 0; rb < 4; ++rb) {
        float v = Lp[rb];
        v += __shfl_xor(v, 16);
        v += __shfl_xor(v, 32);
        if (lg == 0) Lbuf[w * 64 + rb * 16 + lr] = v;
    }
    // same-wave producer/consumer: no barrier needed
    u16* og = ob + (size_t)bp * 16384 + w * 4096;
#pragma unroll
    for (int rb = 0; rb < 4; ++rb)
#pragma unroll
        for (int r = 0; r < 4; ++r) {
            float inv = 1.f / Lbuf[w * 64 + rb * 16 + lg * 4 + r];
#pragma unroll
            for (int sb = 0; sb < 4; ++sb)
                og[(rb * 16 + lg * 4 + r) * 64 + sb * 16 + lr] = f2bf(Oacc[rb][sb][r] * inv);
        }
}

// ---------------------------------------------------------------------------
// Kernel 4: out projection out[b][o2][pos] = sum_c2 WoutB[o2][c2]*ob[b][c2][pos].
// Final f32 output is never re-read -> NON-TEMPORAL stores.
// ---------------------------------------------------------------------------
__global__ __launch_bounds__(256) void k_out(
    const u16* __restrict__ ob, const u16* __restrict__ WoutB,
    float* __restrict__ out)
{
    __shared__ u16 OT[64 * 128];
    const int t = threadIdx.x, w = t >> 6, l = t & 63, lr = l & 15, lg = l >> 4;
    const int pos0 = blockIdx.x * 64;
    const int b = blockIdx.y;
    const u16* obp = ob + (size_t)b * 8388608;
    float* op = out + (size_t)b * 2097152;

    ffrag zf = {0.f, 0.f, 0.f, 0.f};
    ffrag acc[2][4];
#pragma unroll
    for (int rb = 0; rb < 2; ++rb)
#pragma unroll
        for (int nb = 0; nb < 4; ++nb) acc[rb][nb] = zf;

    for (int kc = 0; kc < 4; ++kc) {
        __syncthreads();
#pragma unroll
        for (int it = 0; it < 4; ++it) {
            int g = it * 256 + t;
            int cl = g >> 3, pk = g & 7;
            uint4 v = *(const uint4*)(obp + (size_t)(kc * 128 + cl) * 16384 + pos0 + pk * 8);
            u16 tmp[8];
            *(uint4*)tmp = v;
#pragma unroll
            for (int e = 0; e < 8; ++e) {
                int pos_l = pk * 8 + e;
                OT[pos_l * 128 + (((cl >> 3) ^ sw(pos_l)) << 3) + (cl & 7)] = tmp[e];
            }
        }
        __syncthreads();

#pragma unroll
        for (int kk = 0; kk < 4; ++kk) {
            bfrag Af[2];
#pragma unroll
            for (int rb = 0; rb < 2; ++rb)
                Af[rb] = *(const bfrag*)(WoutB + (size_t)(w * 32 + rb * 16 + lr) * 512 + kc * 128 + kk * 32 + lg * 8);
#pragma unroll
            for (int nb = 0; nb < 4; ++nb) {
                int pos_l = nb * 16 + lr;
                bfrag B = *(const bfrag*)&OT[pos_l * 128 + (((kk * 4 + lg) ^ sw(pos_l)) << 3)];
#pragma unroll
                for (int rb = 0; rb < 2; ++rb)
                    acc[rb][nb] = MFMA16(Af[rb], B, acc[rb][nb]);
            }
        }
    }

#pragma unroll
    for (int rb = 0; rb < 2; ++rb)
#pragma unroll
        for (int nb = 0; nb < 4; ++nb)
#pragma unroll
            for (int r = 0; r < 4; ++r)
                __builtin_nontemporal_store(acc[rb][nb][r],
                    op + (size_t)(w * 32 + rb * 16 + lg * 4 + r) * 16384 + pos0 + nb * 16 + lr);
}

// ---------------------------------------------------------------------------
extern "C" void kernel_launch(void* const* d_in, const int* in_sizes, int n_in,
                              void* d_out, int out_size, void* d_ws, size_t ws_size,
                              hipStream_t stream) {
    const float* x    = (const float*)d_in[0];
    const float* skip = (const float*)d_in[1];
    const float* sinp = (const float*)d_in[2];
    const float* cosp = (const float*)d_in[3];
    const float* Wq   = (const float*)d_in[4];
    const float* Wkv  = (const float*)d_in[5];
    const float* Wout = (const float*)d_in[6];
    float* out = (float*)d_out;

    // workspace (u16 units): qb 16.7M | kbuf 33.5M | vbuf 33.5M | xb 8.4M | WB | WoutB
    u16* qb    = (u16*)d_ws;
    u16* kbp   = qb + (size_t)16777216;
    u16* vbp   = kbp + (size_t)33554432;
    u16* xbp   = vbp + (size_t)33554432;
    u16* WBp   = xbp + (size_t)8388608;
    u16* WoutB = WBp + (size_t)196608;

    hipLaunchKernelGGL(k_prep, dim3(128), dim3(256), 0, stream,
                       Wq, Wkv, Wout, WBp, WoutB);
    hipLaunchKernelGGL(k_cast, dim3(256, 4), dim3(256), 0, stream,
                       x, skip, xbp);
    hipLaunchKernelGGL(k_proj, dim3(256, 40), dim3(256), 0, stream,
                       xbp, sinp, cosp, WBp, qb, kbp, vbp);
    hipLaunchKernelGGL(k_attn, dim3(1024), dim3(256), 0, stream,
                       qb, kbp, vbp, qb /* in-place output over q */);
    hipLaunchKernelGGL(k_out, dim3(256, 2), dim3(256), 0, stream,
                       qb, WoutB, out);
}

// Round 17
// 148.217 us; speedup vs baseline: 1.1061x; 1.0582x over previous
//
#include <hip/hip_runtime.h>
#include <hip/hip_bf16.h>

// LeWinAttention: q/kv projection + scrambled-reshape windowed attention + out projection.
// q buffer: old layout [b][512 o][16384 pos]. K/V buffers: interleaved layout
// [bkv][i=pos>>6][512 oo][64 d] (contiguous 16KB per k_proj block).
// Round 17: exp2f (slow libm) -> __builtin_amdgcn_exp2f (raw v_exp_f32).
// q stays pre-scaled by 0.125*log2e in k_proj.

typedef unsigned short u16;
using bfrag = __attribute__((ext_vector_type(8))) short;   // 8 x bf16
using ffrag = __attribute__((ext_vector_type(4))) float;   // 4 x f32 accum
using s4v   = __attribute__((ext_vector_type(4))) short;   // 4 x bf16 (8B)
using u32x4 = __attribute__((ext_vector_type(4))) unsigned int;  // 16B, nt-store capable

#define MFMA16(a, b, c) __builtin_amdgcn_mfma_f32_16x16x32_bf16((a), (b), (c), 0, 0, 0)
#define QSCALE 0.1803368801111204f   // 0.125 * log2(e)

__device__ __forceinline__ u16 f2bf(float f) {
    __hip_bfloat16 h = __float2bfloat16(f);
    u16 u;
    __builtin_memcpy(&u, &h, 2);
    return u;
}

// bijective slot swizzle: distinct over {pos=base+lr} AND {pos=8k+e} patterns
__device__ __forceinline__ int sw(int p) { return (p ^ (p >> 3)) & 15; }

// ---------------------------------------------------------------------------
// Kernel 0: cast Wq (512x128), Wkv (1024x128), Wout (128x512) f32 -> bf16.
// ---------------------------------------------------------------------------
__global__ __launch_bounds__(256) void k_prep(
    const float* __restrict__ Wq, const float* __restrict__ Wkv,
    const float* __restrict__ Wout, u16* __restrict__ WB, u16* __restrict__ WoutB)
{
    int i8 = (blockIdx.x * 256 + threadIdx.x) * 8;
    const float* src;
    u16* dst;
    if (i8 < 65536)       { src = Wq + i8;            dst = WB + i8; }
    else if (i8 < 196608) { src = Wkv + (i8 - 65536); dst = WB + i8; }
    else                  { src = Wout + (i8 - 196608); dst = WoutB + (i8 - 196608); }
    float4 a = *(const float4*)src;
    float4 b = *(const float4*)(src + 4);
    u16 tmp[8];
    tmp[0] = f2bf(a.x); tmp[1] = f2bf(a.y); tmp[2] = f2bf(a.z); tmp[3] = f2bf(a.w);
    tmp[4] = f2bf(b.x); tmp[5] = f2bf(b.y); tmp[6] = f2bf(b.z); tmp[7] = f2bf(b.w);
    *(uint4*)dst = *(uint4*)tmp;
}

// ---------------------------------------------------------------------------
// Kernel 1: transpose-cast x,skip f32 [c][pos] -> xb bf16 [plane][pos][c] linear.
// ---------------------------------------------------------------------------
__global__ __launch_bounds__(256) void k_cast(
    const float* __restrict__ x, const float* __restrict__ skip,
    u16* __restrict__ xb)
{
    __shared__ float LT[128 * 65];
    const int t = threadIdx.x;
    const int pos0 = blockIdx.x * 64;
    const int p = blockIdx.y;
    const float* src = (p < 2) ? (x + (size_t)p * 2097152)
                               : (skip + (size_t)(p - 2) * 2097152);
    u16* dst = xb + (size_t)p * 2097152;

#pragma unroll
    for (int it = 0; it < 8; ++it) {
        int idx = it * 256 + t;
        int c = idx >> 4, p4 = (idx & 15) * 4;
        float4 v = *(const float4*)(src + (size_t)c * 16384 + pos0 + p4);
        LT[c * 65 + p4 + 0] = v.x;
        LT[c * 65 + p4 + 1] = v.y;
        LT[c * 65 + p4 + 2] = v.z;
        LT[c * 65 + p4 + 3] = v.w;
    }
    __syncthreads();

#pragma unroll
    for (int it = 0; it < 4; ++it) {
        int g = it * 256 + t;
        int pos_l = g >> 4, chunk = g & 15;
        u16 tmp[8];
#pragma unroll
        for (int j = 0; j < 8; ++j)
            tmp[j] = f2bf(LT[(chunk * 8 + j) * 65 + pos_l]);
        *(uint4*)(dst + (size_t)(pos0 + pos_l) * 128 + chunk * 8) = *(uint4*)tmp;
    }
}

// ---------------------------------------------------------------------------
// Kernel 2: projection GEMM + RoPE epilogue (round-13 version + QSCALE on q).
// grid = (256 pos-tiles of 64, 40 row-tiles).
// ---------------------------------------------------------------------------
__global__ __launch_bounds__(256, 4) void k_proj(
    const u16* __restrict__ xb, const float* __restrict__ sinp,
    const float* __restrict__ cosp, const u16* __restrict__ WB,
    u16* __restrict__ qb, u16* __restrict__ kbuf, u16* __restrict__ vbuf)
{
    __shared__ u16 BT[64 * 128];      // stage [pos 64][c 128] -> repack [o 128][pos 64]
    __shared__ float2 SC2[64][33];    // {sin,cos} per [o&63][s], pitch 33
    const int t = threadIdx.x;
    const int pos0 = blockIdx.x * 64;
    const int tr = blockIdx.y;
    const int w = t >> 6, l = t & 63, lr = l & 15, lg = l >> 4;

    int WBrow, plane, mode;  // mode: 0 none (v), 1 q-rope, 2 k-rope
    u16* dst;
    const bool contig = (tr >= 8);
    if (tr < 8) {
        int b = tr >> 2, o0 = (tr & 3) * 128;
        WBrow = o0; plane = b; mode = 1;
        dst = qb + (size_t)b * 8388608 + (size_t)o0 * 16384;   // old layout
    } else {
        int t2 = tr - 8;
        int bkv = t2 >> 3, oo0 = (t2 & 7) * 128;
        WBrow = 512 + oo0; plane = bkv;
        if (oo0 < 512) {
            dst = kbuf + (size_t)bkv * 8388608 + (size_t)blockIdx.x * 32768 + (size_t)oo0 * 64;
            mode = 2;
        } else {
            dst = vbuf + (size_t)bkv * 8388608 + (size_t)blockIdx.x * 32768 + (size_t)(oo0 - 512) * 64;
            mode = 0;
        }
    }

    // stage x tile: xb [pos0..pos0+63][128 c] -> BT swizzled (4 uint4 / thread)
    const u16* xsrc = xb + (size_t)plane * 2097152 + (size_t)pos0 * 128;
#pragma unroll
    for (int it = 0; it < 4; ++it) {
        int li = it * 256 + t;          // 0..1023
        int row = li >> 4, chunk = li & 15;
        uint4 v = *(const uint4*)(xsrc + (size_t)row * 128 + chunk * 8);
        *(uint4*)&BT[row * 128 + ((chunk ^ sw(row)) << 3)] = v;
    }

    // stage this block's sin/cos rows interleaved (coalesced 128B rows).
    const int hh = pos0 >> 7;            // posb>>7, block-uniform
    const int wwhi = blockIdx.x & 1;     // ww>>6, block-uniform
    if (mode != 0) {
        const int hb = hh >> 6;
        const int ridx = (hh & 63) * 2 + wwhi;
#pragma unroll
        for (int e = 0; e < 2; ++e) {
            int g = e * 256 + t;          // 0..511
            int row = g >> 3;             // o&63
            int q = g & 7;                // float4 slot in the 32-f row
            size_t base = ((size_t)(row * 2 + hb) * 128 + ridx) * 32 + q * 4;
            float4 sv4 = *(const float4*)(sinp + base);
            float4 cv4 = *(const float4*)(cosp + base);
            SC2[row][q * 4 + 0] = float2{sv4.x, cv4.x};
            SC2[row][q * 4 + 1] = float2{sv4.y, cv4.y};
            SC2[row][q * 4 + 2] = float2{sv4.z, cv4.z};
            SC2[row][q * 4 + 3] = float2{sv4.w, cv4.w};
        }
    }

    ffrag zf = {0.f, 0.f, 0.f, 0.f};
    ffrag acc[4][2];   // [mb = pos 16-block][nb = o 16-block within wave's 32]
#pragma unroll
    for (int mb = 0; mb < 4; ++mb)
#pragma unroll
        for (int nb = 0; nb < 2; ++nb) acc[mb][nb] = zf;

    __syncthreads();

#pragma unroll
    for (int kk = 0; kk < 4; ++kk) {
        bfrag A[4], B[2];
#pragma unroll
        for (int mb = 0; mb < 4; ++mb) {
            int pos_l = mb * 16 + lr;
            A[mb] = *(const bfrag*)&BT[pos_l * 128 + (((kk * 4 + lg) ^ sw(pos_l)) << 3)];
        }
#pragma unroll
        for (int nb = 0; nb < 2; ++nb)
            B[nb] = *(const bfrag*)(WB + (size_t)(WBrow + w * 32 + nb * 16 + lr) * 128 + kk * 32 + lg * 8);
#pragma unroll
        for (int mb = 0; mb < 4; ++mb)
#pragma unroll
            for (int nb = 0; nb < 2; ++nb)
                acc[mb][nb] = MFMA16(A[mb], B[nb], acc[mb][nb]);
    }

    __syncthreads();  // x-tile reads AND SC2 writes complete; BT reused as repack

    // epilogue: lane holds 4 consecutive pos (register r) at one o (lane).
    // RoPE active iff pos_l < 32 <=> mb < 2. q output pre-scaled by QSCALE.
#pragma unroll
    for (int mb = 0; mb < 4; ++mb) {
        const bool roped = (mode != 0) && (mb < 2);
#pragma unroll
        for (int nb = 0; nb < 2; ++nb) {
            int o_l = w * 32 + nb * 16 + lr;
            int p0 = mb * 16 + lg * 4;          // pos_l base of quad
            ffrag v4 = acc[mb][nb];
            if (roped) {
                const int ob63 = o_l & 63;
#pragma unroll
                for (int r = 0; r < 4; ++r) {
                    float2 sc = SC2[ob63][p0 + r];       // one b64 read: {sin,cos}
                    float sg = (r & 1) ? sc.x : -sc.x;   // rotate_half: -even, +odd
                    v4[r] = (mode == 1) ? v4[r] * (sc.y + sg)        // q
                                        : v4[r] * (1.f + sg) + sc.y; // k (ref's "+cos")
                }
            }
            if (mode == 1) {     // pre-scale q by 0.125*log2e (softmax uses exp2)
#pragma unroll
                for (int r = 0; r < 4; ++r) v4[r] *= QSCALE;
            }
            s4v pk;
            pk[0] = (short)f2bf(v4[0]); pk[1] = (short)f2bf(v4[1]);
            pk[2] = (short)f2bf(v4[2]); pk[3] = (short)f2bf(v4[3]);
            int slot = p0 >> 3;                 // 0..7
            *(s4v*)&BT[o_l * 64 + ((slot ^ (o_l & 7)) << 3) + (p0 & 4)] = pk;
        }
    }

    // PER-WAVE store (same-wave producer/consumer; NO final barrier):
    // wave w's epilogue wrote exactly repack rows [w*32, w*32+32).
#pragma unroll
    for (int it = 0; it < 4; ++it) {
        int i = it * 64 + l;                 // 0..255 within wave's 32-row region
        int row = w * 32 + (i >> 3);
        int slot = i & 7;
        u32x4 v = *(const u32x4*)&BT[row * 64 + ((slot ^ (row & 7)) << 3)];
        size_t goff = contig ? ((size_t)row * 64 + slot * 8)
                             : ((size_t)row * 16384 + pos0 + slot * 8);
        __builtin_nontemporal_store(v, (u32x4*)(dst + goff));
    }
}

// ---------------------------------------------------------------------------
// Kernel 3: windowed attention — 4 waves x 64 q-rows (round-13 structure),
// softmax via raw v_exp_f32 (__builtin_amdgcn_exp2f; q pre-scaled in k_proj).
// ---------------------------------------------------------------------------
__global__ __launch_bounds__(256) void k_attn(
    const u16* __restrict__ qb, const u16* __restrict__ kbuf,
    const u16* __restrict__ vbuf, u16* __restrict__ ob)
{
    __shared__ u16 Ks[64 * 64];      // [j][d-chunk ^ (j&7)]
    __shared__ u16 Vt[64 * 64];      // [d][j-chunk ^ s(d)], s(d)=(d&7)^((d>>3)&7)
    __shared__ u16 Ps[4][64 * 40];   // per wave: [i_local 64][j-half 32, pitch 40]
    __shared__ float Lbuf[256];

    const int bp = blockIdx.x;
    const int t = threadIdx.x, w = t >> 6, l = t & 63, lr = l & 15, lg = l >> 4;

    const u16* Qg = qb + (size_t)bp * 16384 + w * 4096;   // wave's 64 q-rows

    bfrag Qf[4][2];
#pragma unroll
    for (int rb = 0; rb < 4; ++rb)
#pragma unroll
        for (int dk = 0; dk < 2; ++dk)
            Qf[rb][dk] = *(const bfrag*)(Qg + (rb * 16 + lr) * 64 + dk * 32 + lg * 8);

    ffrag zf = {0.f, 0.f, 0.f, 0.f};
    ffrag Oacc[4][4];
#pragma unroll
    for (int rb = 0; rb < 4; ++rb)
#pragma unroll
        for (int sb = 0; sb < 4; ++sb) Oacc[rb][sb] = zf;
    float Lp[4] = {0.f, 0.f, 0.f, 0.f};

    // staging: threads 0..127 stage K, 128..255 stage V (64B each per chunk)
    const int tk = t & 127, sj = tk >> 1, half = tk & 1;
    const bool isK = (t < 128);
    const size_t kvoff = (size_t)(bp >> 8) * 8388608 + (size_t)(bp & 255) * 128;
    const u16* gsb = (isK ? kbuf : vbuf) + kvoff;
    #define KVOFF(c) ((size_t)(((c) & 3) * 64 + sj) * 32768 + (size_t)(((c) >> 2) * 64) + half * 32)

    uint4 r0 = *(const uint4*)(gsb + KVOFF(0));          // prefetch chunk 0 (64B)
    uint4 r1 = *(const uint4*)(gsb + KVOFF(0) + 8);
    uint4 r2 = *(const uint4*)(gsb + KVOFF(0) + 16);
    uint4 r3 = *(const uint4*)(gsb + KVOFF(0) + 24);

    for (int c = 0; c < 8; ++c) {
        __syncthreads();
        if (isK) {
            *(uint4*)&Ks[sj * 64 + (((half * 4 + 0) ^ (sj & 7)) << 3)] = r0;
            *(uint4*)&Ks[sj * 64 + (((half * 4 + 1) ^ (sj & 7)) << 3)] = r1;
            *(uint4*)&Ks[sj * 64 + (((half * 4 + 2) ^ (sj & 7)) << 3)] = r2;
            *(uint4*)&Ks[sj * 64 + (((half * 4 + 3) ^ (sj & 7)) << 3)] = r3;
        } else {
            u16 tmp[32];
            *(uint4*)&tmp[0] = r0;
            *(uint4*)&tmp[8] = r1;
            *(uint4*)&tmp[16] = r2;
            *(uint4*)&tmp[24] = r3;
            const int chunk = sj >> 3, jl = sj & 7;
#pragma unroll
            for (int e = 0; e < 32; ++e) {
                int d = half * 32 + e;
                int s = (d & 7) ^ ((d >> 3) & 7);
                Vt[d * 64 + ((chunk ^ s) << 3) + jl] = tmp[e];   // V^T[d][j]
            }
        }
        __syncthreads();
        if (c < 7) {
            r0 = *(const uint4*)(gsb + KVOFF(c + 1));
            r1 = *(const uint4*)(gsb + KVOFF(c + 1) + 8);
            r2 = *(const uint4*)(gsb + KVOFF(c + 1) + 16);
            r3 = *(const uint4*)(gsb + KVOFF(c + 1) + 24);
        }

#pragma unroll
        for (int jh = 0; jh < 2; ++jh) {
#pragma unroll
            for (int jtl = 0; jtl < 2; ++jtl) {
                const int jt = jh * 2 + jtl;
                bfrag Kf[2];
#pragma unroll
                for (int dk = 0; dk < 2; ++dk)
                    Kf[dk] = *(const bfrag*)&Ks[(jt * 16 + lr) * 64 + (((dk * 4 + lg) ^ (lr & 7)) << 3)];
#pragma unroll
                for (int rb = 0; rb < 4; ++rb) {
                    ffrag sf = zf;
                    __builtin_amdgcn_s_setprio(1);
                    sf = MFMA16(Kf[0], Qf[rb][0], sf);   // D[j_loc=lg*4+r][i_loc=lr]
                    sf = MFMA16(Kf[1], Qf[rb][1], sf);
                    __builtin_amdgcn_s_setprio(0);
                    float e0 = __builtin_amdgcn_exp2f(sf[0]);   // raw v_exp_f32
                    float e1 = __builtin_amdgcn_exp2f(sf[1]);
                    float e2 = __builtin_amdgcn_exp2f(sf[2]);
                    float e3 = __builtin_amdgcn_exp2f(sf[3]);
                    Lp[rb] += (e0 + e1) + (e2 + e3);
                    s4v pk;
                    pk[0] = (short)f2bf(e0); pk[1] = (short)f2bf(e1);
                    pk[2] = (short)f2bf(e2); pk[3] = (short)f2bf(e3);
                    *(s4v*)&Ps[w][(rb * 16 + lr) * 40 + jtl * 16 + lg * 4] = pk;
                }
            }

            bfrag Vf[4];
#pragma unroll
            for (int sb = 0; sb < 4; ++sb) {
                int d = sb * 16 + lr;
                int s = (d & 7) ^ ((d >> 3) & 7);
                Vf[sb] = *(const bfrag*)&Vt[d * 64 + (((jh * 4 + lg) ^ s) << 3)];
            }
            __builtin_amdgcn_s_setprio(1);
#pragma unroll
            for (int rb = 0; rb < 4; ++rb) {
                bfrag Pf = *(const bfrag*)&Ps[w][(rb * 16 + lr) * 40 + lg * 8];
#pragma unroll
                for (int sb = 0; sb < 4; ++sb)
                    Oacc[rb][sb] = MFMA16(Pf, Vf[sb], Oacc[rb][sb]);  // D[i=lg*4+r][d=lr]
            }
            __builtin_amdgcn_s_setprio(0);
        }
    }
    #undef KVOFF

#pragma unroll
    for (int rb = 0; rb < 4; ++rb) {
        float v = Lp[rb];
        v += __shfl_xor(v, 16);
        v += __shfl_xor(v, 32);
        if (lg == 0) Lbuf[w * 64 + rb * 16 + lr] = v;
    }
    // same-wave producer/consumer: no barrier needed
    u16* og = ob + (size_t)bp * 16384 + w * 4096;
#pragma unroll
    for (int rb = 0; rb < 4; ++rb)
#pragma unroll
        for (int r = 0; r < 4; ++r) {
            float inv = 1.f / Lbuf[w * 64 + rb * 16 + lg * 4 + r];
#pragma unroll
            for (int sb = 0; sb < 4; ++sb)
                og[(rb * 16 + lg * 4 + r) * 64 + sb * 16 + lr] = f2bf(Oacc[rb][sb][r] * inv);
        }
}

// ---------------------------------------------------------------------------
// Kernel 4: out projection out[b][o2][pos] = sum_c2 WoutB[o2][c2]*ob[b][c2][pos].
// Final f32 output is never re-read -> NON-TEMPORAL stores.
// ---------------------------------------------------------------------------
__global__ __launch_bounds__(256) void k_out(
    const u16* __restrict__ ob, const u16* __restrict__ WoutB,
    float* __restrict__ out)
{
    __shared__ u16 OT[64 * 128];
    const int t = threadIdx.x, w = t >> 6, l = t & 63, lr = l & 15, lg = l >> 4;
    const int pos0 = blockIdx.x * 64;
    const int b = blockIdx.y;
    const u16* obp = ob + (size_t)b * 8388608;
    float* op = out + (size_t)b * 2097152;

    ffrag zf = {0.f, 0.f, 0.f, 0.f};
    ffrag acc[2][4];
#pragma unroll
    for (int rb = 0; rb < 2; ++rb)
#pragma unroll
        for (int nb = 0; nb < 4; ++nb) acc[rb][nb] = zf;

    for (int kc = 0; kc < 4; ++kc) {
        __syncthreads();
#pragma unroll
        for (int it = 0; it < 4; ++it) {
            int g = it * 256 + t;
            int cl = g >> 3, pk = g & 7;
            uint4 v = *(const uint4*)(obp + (size_t)(kc * 128 + cl) * 16384 + pos0 + pk * 8);
            u16 tmp[8];
            *(uint4*)tmp = v;
#pragma unroll
            for (int e = 0; e < 8; ++e) {
                int pos_l = pk * 8 + e;
                OT[pos_l * 128 + (((cl >> 3) ^ sw(pos_l)) << 3) + (cl & 7)] = tmp[e];
            }
        }
        __syncthreads();

#pragma unroll
        for (int kk = 0; kk < 4; ++kk) {
            bfrag Af[2];
#pragma unroll
            for (int rb = 0; rb < 2; ++rb)
                Af[rb] = *(const bfrag*)(WoutB + (size_t)(w * 32 + rb * 16 + lr) * 512 + kc * 128 + kk * 32 + lg * 8);
#pragma unroll
            for (int nb = 0; nb < 4; ++nb) {
                int pos_l = nb * 16 + lr;
                bfrag B = *(const bfrag*)&OT[pos_l * 128 + (((kk * 4 + lg) ^ sw(pos_l)) << 3)];
#pragma unroll
                for (int rb = 0; rb < 2; ++rb)
                    acc[rb][nb] = MFMA16(Af[rb], B, acc[rb][nb]);
            }
        }
    }

#pragma unroll
    for (int rb = 0; rb < 2; ++rb)
#pragma unroll
        for (int nb = 0; nb < 4; ++nb)
#pragma unroll
            for (int r = 0; r < 4; ++r)
                __builtin_nontemporal_store(acc[rb][nb][r],
                    op + (size_t)(w * 32 + rb * 16 + lg * 4 + r) * 16384 + pos0 + nb * 16 + lr);
}

// ---------------------------------------------------------------------------
extern "C" void kernel_launch(void* const* d_in, const int* in_sizes, int n_in,
                              void* d_out, int out_size, void* d_ws, size_t ws_size,
                              hipStream_t stream) {
    const float* x    = (const float*)d_in[0];
    const float* skip = (const float*)d_in[1];
    const float* sinp = (const float*)d_in[2];
    const float* cosp = (const float*)d_in[3];
    const float* Wq   = (const float*)d_in[4];
    const float* Wkv  = (const float*)d_in[5];
    const float* Wout = (const float*)d_in[6];
    float* out = (float*)d_out;

    // workspace (u16 units): qb 16.7M | kbuf 33.5M | vbuf 33.5M | xb 8.4M | WB | WoutB
    u16* qb    = (u16*)d_ws;
    u16* kbp   = qb + (size_t)16777216;
    u16* vbp   = kbp + (size_t)33554432;
    u16* xbp   = vbp + (size_t)33554432;
    u16* WBp   = xbp + (size_t)8388608;
    u16* WoutB = WBp + (size_t)196608;

    hipLaunchKernelGGL(k_prep, dim3(128), dim3(256), 0, stream,
                       Wq, Wkv, Wout, WBp, WoutB);
    hipLaunchKernelGGL(k_cast, dim3(256, 4), dim3(256), 0, stream,
                       x, skip, xbp);
    hipLaunchKernelGGL(k_proj, dim3(256, 40), dim3(256), 0, stream,
                       xbp, sinp, cosp, WBp, qb, kbp, vbp);
    hipLaunchKernelGGL(k_attn, dim3(1024), dim3(256), 0, stream,
                       qb, kbp, vbp, qb /* in-place output over q */);
    hipLaunchKernelGGL(k_out, dim3(256, 2), dim3(256), 0, stream,
                       qb, WoutB, out);
}